// Round 17
// baseline (3313.292 us; speedup 1.0000x reference)
//
#include <hip/hip_runtime.h>

#define HID 768
// --- W-stationary path ---
#define WPT 32     // words per tile (128 rows)
#define MR 128
// --- r9 fallback path ---
#define WPB 16
#define ROWS 64
#define BK 64
#define NCH 12

typedef __attribute__((ext_vector_type(4))) float f32x4;
typedef __attribute__((ext_vector_type(8))) short s16x8;
typedef __attribute__((ext_vector_type(4))) short s16x4;

__device__ inline short f2bf(float f) {
  unsigned u = __builtin_bit_cast(unsigned, f);
  u = (u + 0x7fffu + ((u >> 16) & 1u)) >> 16;
  return (short)(unsigned short)u;
}
__device__ inline float bf2f(short s) {
  unsigned u = ((unsigned)(unsigned short)s) << 16;
  return __builtin_bit_cast(float, u);
}
__device__ inline float fast_tanh(float v) {
  float e = exp2f(v * 2.885390081777927f);   // e^{2v}
  return 1.0f - 2.0f * __builtin_amdgcn_rcpf(e + 1.0f);
}
__device__ inline s16x8 pack8(f32x4 f0, f32x4 f1) {
  s16x8 p;
  p[0]=f2bf(f0[0]); p[1]=f2bf(f0[1]); p[2]=f2bf(f0[2]); p[3]=f2bf(f0[3]);
  p[4]=f2bf(f1[0]); p[5]=f2bf(f1[1]); p[6]=f2bf(f1[2]); p[7]=f2bf(f1[3]);
  return p;
}
__device__ inline s16x4 pack4(f32x4 f) {
  s16x4 p;
  p[0]=f2bf(f[0]); p[1]=f2bf(f[1]); p[2]=f2bf(f[2]); p[3]=f2bf(f[3]);
  return p;
}

// ---- pre-pass 1: W fp32 -> bf16 in MFMA FRAGMENT ORDER (verified r7-r16) ----
// frag(kc, t): lane l holds W[t*16+(l&15)][kc*32+(l>>4)*8 .. +8], 1KB/frag.
__global__ void wconv_kernel(const float* __restrict__ W, short* __restrict__ Wb, int n64) {
  int gid = blockIdx.x * blockDim.x + threadIdx.x;
  if (gid >= n64) return;                  // 24*48*64 = 73728
  int lane = gid & 63;
  int frag = gid >> 6;
  int kc = frag / 48;
  int t  = frag - kc * 48;
  int col = t * 16 + (lane & 15);
  int k0  = kc * 32 + (lane >> 4) * 8;
  const float* src = W + (size_t)col * HID + k0;
  f32x4 f0 = *(const f32x4*)src;
  f32x4 f1 = *(const f32x4*)(src + 4);
  *(s16x8*)(Wb + (size_t)gid * 8) = pack8(f0, f1);
}

// ---- pre-pass 2: x fp32 -> bf16 in MFMA FRAGMENT ORDER (64-row bands) ----
// frag f = (band*24 + kc)*4 + fr; lane l holds
// x[band*64 + fr*16 + (l&15)][kc*32 + (l>>4)*8 .. +8]. Write fully coalesced.
__global__ void xconv_kernel(const float* __restrict__ x, short* __restrict__ Xb,
                             int nthreads, int n_sub) {
  int gid = blockIdx.x * blockDim.x + threadIdx.x;
  if (gid >= nthreads) return;
  int lane = gid & 63;
  int f = gid >> 6;
  int fr = f & 3;
  int rest = f >> 2;
  int kc = rest % 24;
  int band = rest / 24;
  int row = band * 64 + fr * 16 + (lane & 15);
  int k0  = kc * 32 + (lane >> 4) * 8;
  f32x4 a = {0,0,0,0}, b = {0,0,0,0};
  if (row < n_sub) {
    const float* s = x + (size_t)row * HID + k0;
    a = *(const f32x4*)s;
    b = *(const f32x4*)(s + 4);
  }
  *(s16x8*)(Xb + (size_t)gid * 8) = pack8(a, b);
}

// ==== main: W-STATIONARY, barrier-free inner loop ====
// 512 thr / 8 waves; wave owns 16 cols x full K (W frags in 96 VGPRs).
// Tile 128 rows x 128 cols; 6 col-sibling blocks per tile (XCD-swizzled);
// inner loop: 8 A-frag global loads + 8 MFMA per K-chunk, NO barriers.
__global__ __launch_bounds__(512, 1) void gemm_ws(
    const short* __restrict__ Xb, const short* __restrict__ Wb,
    const float* __restrict__ x, const float* __restrict__ bias,
    const float* __restrict__ scw, const int* __restrict__ mapping,
    float* __restrict__ out, int num_words,
    float* __restrict__ s_glob, int* __restrict__ cnt, int swz)
{
  __shared__ float s_lds[MR];
  __shared__ int lastflag;

  const int tid = threadIdx.x;
  int tile, strip;
  if (swz) {                     // 6 siblings differ by 8 in blockIdx -> same XCD
    int q = blockIdx.x / 48;
    int rr = blockIdx.x - q * 48;
    tile = q * 8 + (rr & 7);
    strip = rr >> 3;
  } else {
    tile = blockIdx.x / 6;
    strip = blockIdx.x - tile * 6;
  }
  const int w0 = tile * WPT;
  const int wlast = min(w0 + WPT - 1, num_words - 1);
  const int r0 = mapping[2 * w0];
  const int r1 = mapping[2 * wlast + 1];
  const int nrows = min(r1 - r0, MR);

  const int lane = tid & 63;
  const int wave = tid >> 6;     // 0..7
  const int l15 = lane & 15;
  const int lk  = lane >> 4;
  const int t = strip * 8 + wave;        // col-tile 0..47 (16 cols each)

  if (tid < MR) s_lds[tid] = 0.0f;

  // ---- W fragments: 24 x s16x8 = 96 VGPR, resident all kernel ----
  s16x8 wf[24];
  #pragma unroll
  for (int kc = 0; kc < 24; ++kc)
    wf[kc] = *(const s16x8*)(Wb + ((size_t)kc * 48 + t) * 512 + lane * 8);

  f32x4 acc[8];
  #pragma unroll
  for (int fr = 0; fr < 8; ++fr) acc[fr] = (f32x4){0,0,0,0};

  // ---- K loop: barrier-free. 8 A-frags (global, fragment-ordered bf16,
  //      identical addresses across the 8 waves -> L1 broadcast) + 8 MFMA ----
  const int band0 = tile * 2;
  const short* xb0 = Xb + lane * 8;
  #pragma unroll
  for (int kc = 0; kc < 24; ++kc) {
    s16x8 af[8];
    #pragma unroll
    for (int fr = 0; fr < 8; ++fr)
      af[fr] = *(const s16x8*)(xb0 +
          (size_t)(((band0 + (fr >> 2)) * 24 + kc) * 4 + (fr & 3)) * 512);
    #pragma unroll
    for (int fr = 0; fr < 8; ++fr)
      acc[fr] = __builtin_amdgcn_mfma_f32_16x16x32_bf16(af[fr], wf[kc], acc[fr], 0, 0, 0);
    if ((kc & 3) == 3)
      asm volatile("s_barrier" ::: "memory");   // wave alignment (L1 sharing)
  }

  // ---- tanh + scorer dot (wave's 16 cols), 16-lane reduce -> s_lds ----
  __syncthreads();   // s_lds init visible
  const float wv = scw[t * 16 + l15];
  const float bv = bias[t * 16 + l15];
  #pragma unroll
  for (int fr = 0; fr < 8; ++fr) {
    #pragma unroll
    for (int r = 0; r < 4; ++r) {
      float v = fast_tanh(acc[fr][r] + bv) * wv;
      v += __shfl_xor(v, 1);
      v += __shfl_xor(v, 2);
      v += __shfl_xor(v, 4);
      v += __shfl_xor(v, 8);
      if (l15 == 0) atomicAdd(&s_lds[fr * 16 + lk * 4 + r], v);
    }
  }
  __syncthreads();

  // publish strip partials + counter handshake (r11/r13-verified)
  if (tid < nrows) atomicAdd(&s_glob[r0 + tid], s_lds[tid]);
  __syncthreads();
  if (tid == 0) {
    __threadfence();
    int old = atomicAdd(&cnt[tile], 1);
    lastflag = (old == 5) ? 1 : 0;
  }
  __syncthreads();
  if (!lastflag) return;
  __threadfence();

  if (tid < MR)
    s_lds[tid] = (tid < nrows)
        ? __hip_atomic_load(&s_glob[r0 + tid], __ATOMIC_RELAXED, __HIP_MEMORY_SCOPE_AGENT)
        : 0.0f;
  __syncthreads();

  // ---- per-word softmax + weighted sum (x fp32), 8 waves x 4 words ----
  const float LOG2E = 1.4426950408889634f;
  for (int wi = wave; wi < WPT; wi += 8) {
    int gw = w0 + wi;
    if (gw >= num_words) break;
    int grs = mapping[2 * gw];
    int lrs = grs - r0;
    int cnt_ = min(mapping[2 * gw + 1] - r0, nrows) - lrs;
    float mmax = -3.0e38f;
    for (int i = 0; i < cnt_; ++i) mmax = fmaxf(mmax, s_lds[lrs + i]);
    float denom = 0.0f;
    for (int i = 0; i < cnt_; ++i) denom += exp2f((s_lds[lrs + i] - mmax) * LOG2E);
    float rden = (denom > 0.0f) ? (1.0f / denom) : 0.0f;
    float pbuf[8];
    #pragma unroll
    for (int i = 0; i < 8; ++i)
      pbuf[i] = (i < cnt_) ? exp2f((s_lds[lrs + i] - mmax) * LOG2E) * rden : 0.0f;
    #pragma unroll
    for (int j = 0; j < 3; ++j) {
      int col = j * 256 + lane * 4;
      const float* xb = x + (size_t)grs * HID + col;
      f32x4 o = {0, 0, 0, 0};
      #pragma unroll
      for (int i = 0; i < 8; ++i) {
        if (i < cnt_) {
          f32x4 xv = *(const f32x4*)(xb + (size_t)i * HID);
          o[0] += pbuf[i] * xv[0];
          o[1] += pbuf[i] * xv[1];
          o[2] += pbuf[i] * xv[2];
          o[3] += pbuf[i] * xv[3];
        }
      }
      for (int i = 8; i < cnt_; ++i) {   // generality tail
        float p = exp2f((s_lds[lrs + i] - mmax) * LOG2E) * rden;
        f32x4 xv = *(const f32x4*)(xb + (size_t)i * HID);
        o[0] += p * xv[0];
        o[1] += p * xv[1];
        o[2] += p * xv[2];
        o[3] += p * xv[3];
      }
      *(f32x4*)(out + (size_t)gw * HID + col) = o;
    }
  }
}

// ==== fallback: r9 fused kernel VERBATIM (best verified: 621 us) ====
template<bool USE_WB>
__global__ __launch_bounds__(1024, 1) void fused_r9(
    const float* __restrict__ x, const short* __restrict__ Wb,
    const float* __restrict__ Wf, const float* __restrict__ bias,
    const float* __restrict__ scw, const int* __restrict__ mapping,
    float* __restrict__ out, int num_words)
{
  __shared__ short Abuf[2 * ROWS * BK];
  __shared__ float s_lds[ROWS];

  const int tid = threadIdx.x;
  const int tile = blockIdx.x;
  const int w0 = tile * WPB;
  const int wlast = min(w0 + WPB - 1, num_words - 1);
  const int r0 = mapping[2 * w0];
  const int r1 = mapping[2 * wlast + 1];
  const int nrows = min(r1 - r0, ROWS);

  const int srow = tid >> 4;
  const int sslot = tid & 15;
  const bool sok = srow < nrows;
  const float* xs = x + (size_t)(r0 + srow) * HID + sslot * 4;
  char* wsw = (char*)Abuf + srow * 128 + ((sslot * 8) ^ ((srow & 7) << 4));

  f32x4 pfA, pfB;

  #define ISSUE(PF, CH) do {                                       \
      PF = sok ? *(const f32x4*)(xs + (CH) * BK) : (f32x4){0,0,0,0}; } while(0)
  #define CVTW(PF, BUFI) do {                                      \
      *(s16x4*)(wsw + (BUFI) * (ROWS * BK * 2)) = pack4(PF); } while(0)
  #define BARRIER() do {                                           \
      asm volatile("s_waitcnt lgkmcnt(0)" ::: "memory");           \
      __builtin_amdgcn_s_barrier(); } while(0)

  if (tid < ROWS) s_lds[tid] = 0.0f;

  const int lane = tid & 63;
  const int wave = tid >> 6;
  const int l15 = lane & 15;
  const int lk  = lane >> 4;
  const int c0  = wave * 48;
  const char* abase = (const char*)Abuf + l15 * 128;
  const int col0 = (lk * 16) ^ ((l15 & 7) << 4);
  const int col1 = col0 ^ 64;

  const short* B2 = Wb + (size_t)(wave * 3) * 512 + lane * 8;
  const float* Bf = Wf + (size_t)(c0 + l15) * HID + lk * 8;

  auto loadB = [&](int n, int kc) -> s16x8 {
    if constexpr (USE_WB) {
      return *(const s16x8*)(B2 + (size_t)kc * 24576 + n * 512);
    } else {
      f32x4 g0 = *(const f32x4*)(Bf + n * (16 * HID) + kc * 32);
      f32x4 g1 = *(const f32x4*)(Bf + n * (16 * HID) + kc * 32 + 4);
      return pack8(g0, g1);
    }
  };

  f32x4 acc[4][3];
  #pragma unroll
  for (int m = 0; m < 4; ++m)
    #pragma unroll
    for (int n = 0; n < 3; ++n) acc[m][n] = (f32x4){0,0,0,0};

  s16x8 bE[3], bO[3];

  ISSUE(pfA, 0);
  ISSUE(pfB, 1);
  #pragma unroll
  for (int n = 0; n < 3; ++n) bE[n] = loadB(n, 0);
  CVTW(pfA, 0);
  BARRIER();

  #define CHUNK(C, PFI, ICH, PFW) do {                                       \
    const int bufi = (C) & 1;                                                \
    const char* ab = abase + bufi * (ROWS * BK * 2);                         \
    _Pragma("unroll")                                                        \
    for (int n = 0; n < 3; ++n) bO[n] = loadB(n, (C) * 2 + 1);               \
    ISSUE(PFI, (ICH) < NCH ? (ICH) : NCH - 1);                               \
    {                                                                        \
      s16x8 a0 = *(const s16x8*)(ab + 0 * (16*128) + col0);                  \
      s16x8 a1 = *(const s16x8*)(ab + 1 * (16*128) + col0);                  \
      s16x8 a2 = *(const s16x8*)(ab + 2 * (16*128) + col0);                  \
      s16x8 a3 = *(const s16x8*)(ab + 3 * (16*128) + col0);                  \
      __builtin_amdgcn_s_setprio(1);                                         \
      _Pragma("unroll")                                                      \
      for (int n = 0; n < 3; ++n) {                                          \
        acc[0][n] = __builtin_amdgcn_mfma_f32_16x16x32_bf16(a0, bE[n], acc[0][n], 0,0,0); \
        acc[1][n] = __builtin_amdgcn_mfma_f32_16x16x32_bf16(a1, bE[n], acc[1][n], 0,0,0); \
        acc[2][n] = __builtin_amdgcn_mfma_f32_16x16x32_bf16(a2, bE[n], acc[2][n], 0,0,0); \
        acc[3][n] = __builtin_amdgcn_mfma_f32_16x16x32_bf16(a3, bE[n], acc[3][n], 0,0,0); \
      }                                                                      \
      __builtin_amdgcn_s_setprio(0);                                         \
    }                                                                        \
    {                                                                        \
      const int tn = (C) * 2 + 2;                                            \
      _Pragma("unroll")                                                      \
      for (int n = 0; n < 3; ++n) bE[n] = loadB(n, tn < 24 ? tn : 23);       \
      s16x8 a0 = *(const s16x8*)(ab + 0 * (16*128) + col1);                  \
      s16x8 a1 = *(const s16x8*)(ab + 1 * (16*128) + col1);                  \
      s16x8 a2 = *(const s16x8*)(ab + 2 * (16*128) + col1);                  \
      s16x8 a3 = *(const s16x8*)(ab + 3 * (16*128) + col1);                  \
      __builtin_amdgcn_s_setprio(1);                                         \
      _Pragma("unroll")                                                      \
      for (int n = 0; n < 3; ++n) {                                          \
        acc[0][n] = __builtin_amdgcn_mfma_f32_16x16x32_bf16(a0, bO[n], acc[0][n], 0,0,0); \
        acc[1][n] = __builtin_amdgcn_mfma_f32_16x16x32_bf16(a1, bO[n], acc[1][n], 0,0,0); \
        acc[2][n] = __builtin_amdgcn_mfma_f32_16x16x32_bf16(a2, bO[n], acc[2][n], 0,0,0); \
        acc[3][n] = __builtin_amdgcn_mfma_f32_16x16x32_bf16(a3, bO[n], acc[3][n], 0,0,0); \
      }                                                                      \
      __builtin_amdgcn_s_setprio(0);                                         \
    }                                                                        \
    if ((C) + 1 < NCH) CVTW(PFW, bufi ^ 1);                                  \
    BARRIER();                                                               \
  } while(0)

  #pragma unroll 1
  for (int ch = 0; ch < NCH; ch += 2) {
    CHUNK(ch,     pfA, ch + 2, pfB);
    CHUNK(ch + 1, pfB, ch + 3, pfA);
  }

  float wvv[3], bvv[3];
  #pragma unroll
  for (int n = 0; n < 3; ++n) {
    int col = c0 + n * 16 + l15;
    wvv[n] = scw[col];
    bvv[n] = bias[col];
  }
  #pragma unroll
  for (int m = 0; m < 4; ++m) {
    #pragma unroll
    for (int r = 0; r < 4; ++r) {
      float v = 0.0f;
      #pragma unroll
      for (int n = 0; n < 3; ++n)
        v += fast_tanh(acc[m][n][r] + bvv[n]) * wvv[n];
      v += __shfl_xor(v, 1);
      v += __shfl_xor(v, 2);
      v += __shfl_xor(v, 4);
      v += __shfl_xor(v, 8);
      if (l15 == 0) atomicAdd(&s_lds[m * 16 + lk * 4 + r], v);
    }
  }
  __syncthreads();

  const float LOG2E = 1.4426950408889634f;
  int gw = w0 + wave;
  if (wave < WPB && gw < num_words) {
    int grs = mapping[2 * gw];
    int lrs = grs - r0;
    int cnt_ = min(mapping[2 * gw + 1] - r0, nrows) - lrs;
    float mmax = -3.0e38f;
    for (int i = 0; i < cnt_; ++i) mmax = fmaxf(mmax, s_lds[lrs + i]);
    float denom = 0.0f;
    for (int i = 0; i < cnt_; ++i) denom += exp2f((s_lds[lrs + i] - mmax) * LOG2E);
    float rden = (denom > 0.0f) ? (1.0f / denom) : 0.0f;
    float pb[8];
    #pragma unroll
    for (int i = 0; i < 8; ++i)
      pb[i] = (i < cnt_) ? exp2f((s_lds[lrs + i] - mmax) * LOG2E) * rden : 0.0f;
    #pragma unroll
    for (int j = 0; j < 3; ++j) {
      int col = j * 256 + lane * 4;
      const float* xb = x + (size_t)grs * HID + col;
      f32x4 o = {0, 0, 0, 0};
      #pragma unroll
      for (int i = 0; i < 8; ++i) {
        if (i < cnt_) {
          f32x4 xv = *(const f32x4*)(xb + (size_t)i * HID);
          o[0] += pb[i] * xv[0];
          o[1] += pb[i] * xv[1];
          o[2] += pb[i] * xv[2];
          o[3] += pb[i] * xv[3];
        }
      }
      for (int i = 8; i < cnt_; ++i) {
        float p = exp2f((s_lds[lrs + i] - mmax) * LOG2E) * rden;
        f32x4 xv = *(const f32x4*)(xb + (size_t)i * HID);
        o[0] += p * xv[0];
        o[1] += p * xv[1];
        o[2] += p * xv[2];
        o[3] += p * xv[3];
      }
      *(f32x4*)(out + (size_t)gw * HID + col) = o;
    }
  }
  #undef ISSUE
  #undef CVTW
  #undef BARRIER
  #undef CHUNK
}

extern "C" void kernel_launch(void* const* d_in, const int* in_sizes, int n_in,
                              void* d_out, int out_size, void* d_ws, size_t ws_size,
                              hipStream_t stream) {
  const float* x    = (const float*)d_in[0];
  const float* W    = (const float*)d_in[1];
  const float* bias = (const float*)d_in[2];
  const float* scw  = (const float*)d_in[3];
  // d_in[4] (scorer bias) shifts every logit equally -> cancels in softmax
  const int* mapping = (const int*)d_in[5];
  float* out = (float*)d_out;

  int num_words = in_sizes[5] / 2;
  int n_sub = in_sizes[0] / HID;
  int bands = (n_sub + 63) >> 6;
  int ntiles = (num_words + WPT - 1) / WPT;

  size_t wb_bytes = (size_t)HID * HID * sizeof(short);        // 1.18 MB
  size_t xb_bytes = (size_t)bands * 24 * 4 * 1024;            // ~403 MB
  size_t sg_bytes = (size_t)n_sub * sizeof(float);
  size_t cb_bytes = (size_t)ntiles * sizeof(int);
  size_t need_big = wb_bytes + xb_bytes + sg_bytes + cb_bytes;

  char* wsb = (char*)d_ws;
  int n64 = (HID / 32) * (HID / 16) * 64;                     // 73728

  if (ws_size >= need_big && (num_words % WPT) == 0) {
    short* Wb     = (short*)wsb;
    short* Xb     = (short*)(wsb + wb_bytes);
    float* s_glob = (float*)(wsb + wb_bytes + xb_bytes);
    int*   cntb   = (int*)(wsb + wb_bytes + xb_bytes + sg_bytes);
    hipMemsetAsync(s_glob, 0, sg_bytes + cb_bytes, stream);
    wconv_kernel<<<(n64 + 255) / 256, 256, 0, stream>>>(W, Wb, n64);
    int nxth = bands * 24 * 4 * 64;
    xconv_kernel<<<(nxth + 255) / 256, 256, 0, stream>>>(x, Xb, nxth, n_sub);
    int swz = (ntiles % 8 == 0) ? 1 : 0;
    gemm_ws<<<ntiles * 6, 512, 0, stream>>>(
        Xb, Wb, x, bias, scw, mapping, out, num_words, s_glob, cntb, swz);
  } else if (ws_size >= wb_bytes) {
    short* Wb = (short*)wsb;
    wconv_kernel<<<(n64 + 255) / 256, 256, 0, stream>>>(W, Wb, n64);
    int nt = (num_words + WPB - 1) / WPB;
    fused_r9<true><<<nt, 1024, 0, stream>>>(x, Wb, W, bias, scw, mapping, out, num_words);
  } else {
    int nt = (num_words + WPB - 1) / WPB;
    fused_r9<false><<<nt, 1024, 0, stream>>>(x, nullptr, W, bias, scw, mapping, out, num_words);
  }
}